// Round 1
// baseline (192.540 us; speedup 1.0000x reference)
//
#include <hip/hip_runtime.h>
#include <hip/hip_bf16.h>

// ---------------- helpers ----------------

#define SWZ(i) ((i) ^ (((i) >> 5) & 15))

__device__ __forceinline__ void gate1q(float2& a0, float2& a1, const float* u) {
    // u: u00r,u00i,u01r,u01i,u10r,u10i,u11r,u11i ; new = U * [a0;a1]
    float n0r = u[0]*a0.x - u[1]*a0.y + u[2]*a1.x - u[3]*a1.y;
    float n0i = u[0]*a0.y + u[1]*a0.x + u[2]*a1.y + u[3]*a1.x;
    float n1r = u[4]*a0.x - u[5]*a0.y + u[6]*a1.x - u[7]*a1.y;
    float n1i = u[4]*a0.y + u[5]*a0.x + u[6]*a1.y + u[7]*a1.x;
    a0.x = n0r; a0.y = n0i; a1.x = n1r; a1.y = n1i;
}

__device__ __forceinline__ void crx_pair(float2& a0, float2& a1, float c, float s) {
    // RX on the (a0,a1) pair: n0 = c*a0 - i*s*a1 ; n1 = -i*s*a0 + c*a1
    float n0r = c*a0.x + s*a1.y;
    float n0i = c*a0.y - s*a1.x;
    float n1r = c*a1.x + s*a0.y;
    float n1i = c*a1.y - s*a0.x;
    a0.x = n0r; a0.y = n0i; a1.x = n1r; a1.y = n1i;
}

template<int K>
__device__ __forceinline__ void apply1q_win(float2* a, const float* u) {
    #pragma unroll
    for (int m = 0; m < 16; ++m) {
        const int j0 = ((m >> K) << (K + 1)) | (m & ((1 << K) - 1));
        gate1q(a[j0], a[j0 | (1 << K)], u);
    }
}

template<int KC, int KT>
__device__ __forceinline__ void crx_win(float2* a, float c, float s) {
    #pragma unroll
    for (int j = 0; j < 32; ++j) {
        if ((j & (1 << KC)) != 0 && (j & (1 << KT)) == 0)
            crx_pair(a[j], a[j | (1 << KT)], c, s);
    }
}

__device__ __forceinline__ void loadU(const float* __restrict__ src, float* u) {
    #pragma unroll
    for (int k = 0; k < 8; ++k) u[k] = src[k];
}

// ---------------- kernel 1: adaptive pool ----------------
// x: (128, 2, 16, 64, 64) f32 -> p: (128, 32), p[b][c*16+dd*4+hh] = mean of 4x16x64 block
__global__ __launch_bounds__(256) void pool_kernel(const float* __restrict__ x,
                                                   float* __restrict__ p) {
    int blk = blockIdx.x;            // b*32 + j
    int b = blk >> 5, j = blk & 31;
    int c = j >> 4, dd = (j >> 2) & 3, hh = j & 3;
    const float4* xb = (const float4*)(x + (((size_t)(b * 2 + c) * 16 + dd * 4) << 12)
                                         + (size_t)hh * 1024);
    int tid = threadIdx.x;
    float sum = 0.f;
    #pragma unroll
    for (int k = 0; k < 4; ++k) {
        int f = k * 256 + tid;           // float4 index 0..1023
        int r = f >> 4, col = f & 15;    // row 0..63 (d'*16+h'), 16 float4 per row
        int off = (r >> 4) * 1024 + (r & 15) * 16 + col;  // float4 units
        float4 v = xb[off];
        sum += v.x + v.y + v.z + v.w;
    }
    #pragma unroll
    for (int o = 1; o < 64; o <<= 1) sum += __shfl_xor(sum, o);
    __shared__ float red[4];
    if ((tid & 63) == 0) red[tid >> 6] = sum;
    __syncthreads();
    if (tid == 0) p[blk] = (red[0] + red[1] + red[2] + red[3]) * (1.0f / 4096.0f);
}

// ---------------- kernel 2: feats + fused gate precompute ----------------
// U layout: U[l][b][q][8] floats ; crxcs[l][q][2] ; also zeroes ev[b][16]
__global__ __launch_bounds__(64) void feats_kernel(const float* __restrict__ p,
                                                   const float* __restrict__ cw,
                                                   const float* __restrict__ cb,
                                                   const float* __restrict__ rot1,
                                                   const float* __restrict__ crx1,
                                                   const float* __restrict__ rot2,
                                                   const float* __restrict__ crx2,
                                                   float* __restrict__ Uws,
                                                   float* __restrict__ crxcs,
                                                   float* __restrict__ ev) {
    int b = blockIdx.x, tid = threadIdx.x;
    __shared__ float pp[32];
    if (tid < 32) pp[tid] = p[b * 32 + tid];
    __syncthreads();
    if (tid >= 16 && tid < 32) ev[b * 16 + (tid - 16)] = 0.f;
    if (tid < 16) {
        int q = tid;
        float f = cb[q];
        #pragma unroll
        for (int jj = 0; jj < 32; ++jj) f += pp[jj] * cw[q * 32 + jj];
        float cr = cosf(0.5f * f), sr = sinf(0.5f * f);
        #pragma unroll
        for (int l = 0; l < 2; ++l) {
            const float* rw = (l == 0 ? rot1 : rot2) + q * 3;
            float phi = rw[0], th = rw[1], om = rw[2];
            float ct = cosf(0.5f * th), st = sinf(0.5f * th);
            float aa = 0.5f * (phi + om), dd = 0.5f * (phi - om);
            float ca = cosf(aa), sa = sinf(aa), cd = cosf(dd), sd = sinf(dd);
            // Rot = [[e^{-ia}ct, -e^{id}st], [e^{-id}st, e^{ia}ct]]
            float R00r =  ct * ca, R00i = -ct * sa;
            float R01r = -st * cd, R01i = -st * sd;
            float R10r =  st * cd, R10i = -st * sd;
            float R11r =  ct * ca, R11i =  ct * sa;
            // U = Rot * RX(f) , RX = [[cr, -i sr], [-i sr, cr]]
            float u0 = cr * R00r + sr * R01i;
            float u1 = cr * R00i - sr * R01r;
            float u2 = cr * R01r + sr * R00i;
            float u3 = cr * R01i - sr * R00r;
            float u4 = cr * R10r + sr * R11i;
            float u5 = cr * R10i - sr * R11r;
            float u6 = cr * R11r + sr * R10i;
            float u7 = cr * R11i - sr * R10r;
            float* dst = Uws + ((size_t)(l * 128 + b) * 16 + q) * 8;
            dst[0] = u0; dst[1] = u1; dst[2] = u2; dst[3] = u3;
            dst[4] = u4; dst[5] = u5; dst[6] = u6; dst[7] = u7;
            if (b == 0) {
                float th2 = (l == 0 ? crx1 : crx2)[q];
                crxcs[(l * 16 + q) * 2 + 0] = cosf(0.5f * th2);
                crxcs[(l * 16 + q) * 2 + 1] = sinf(0.5f * th2);
            }
        }
    }
}

// ---------------- kernel 3: pass A (qubits 0..12 local in LDS chunk) ----------------
// grid: 128 batches * 8 chunks ; 256 threads ; LDS = 8192 float2 = 64 KB
template<int LAYER>
__global__ __launch_bounds__(256) void qstep_a(const float* __restrict__ Uws,
                                               const float* __restrict__ crxcs,
                                               float2* __restrict__ state) {
    __shared__ float2 lds[8192];
    int tid = threadIdx.x;
    int b = blockIdx.x >> 3, chunk = blockIdx.x & 7;
    size_t base = ((size_t)b << 16) + ((size_t)chunk << 13);

    if (LAYER == 0) {
        #pragma unroll
        for (int j = 0; j < 32; ++j) lds[SWZ(j * 256 + tid)] = make_float2(0.f, 0.f);
        if (chunk == 0 && tid == 0) lds[SWZ(0)] = make_float2(1.f, 0.f);
    } else {
        #pragma unroll
        for (int j = 0; j < 32; ++j) lds[SWZ(j * 256 + tid)] = state[base + j * 256 + tid];
    }
    __syncthreads();

    const float* Ub = Uws + (size_t)(LAYER * 128 + b) * 128;   // 16 gates * 8 floats
    const float* cs = crxcs + LAYER * 32;
    float2 a[32];
    float u[8];

    // ---- SR1: window bits 0..4 (qubits 0..4), outer = tid bits -> idx bits 5..12
    {
        #pragma unroll
        for (int j = 0; j < 32; ++j) a[j] = lds[SWZ((tid << 5) | j)];
        loadU(Ub + 0 * 8, u);  apply1q_win<0>(a, u);
        loadU(Ub + 1 * 8, u);  apply1q_win<1>(a, u);
        loadU(Ub + 2 * 8, u);  apply1q_win<2>(a, u);
        loadU(Ub + 3 * 8, u);  apply1q_win<3>(a, u);
        loadU(Ub + 4 * 8, u);  apply1q_win<4>(a, u);
        crx_win<0, 1>(a, cs[0], cs[1]);    // CRX(0,1)
        crx_win<1, 2>(a, cs[2], cs[3]);    // CRX(1,2)
        crx_win<2, 3>(a, cs[4], cs[5]);    // CRX(2,3)
        crx_win<3, 4>(a, cs[6], cs[7]);    // CRX(3,4)
        #pragma unroll
        for (int j = 0; j < 32; ++j) lds[SWZ((tid << 5) | j)] = a[j];
    }
    __syncthreads();

    // ---- SR2: window bits 4..8 (qubits 4..8): idx = (tid&15) | (j<<4) | ((tid>>4)<<9)
    {
        int lo = tid & 15, hi = (tid >> 4) << 9;
        #pragma unroll
        for (int j = 0; j < 32; ++j) a[j] = lds[SWZ(lo | (j << 4) | hi)];
        loadU(Ub + 5 * 8, u);  apply1q_win<1>(a, u);   // qubit 5
        loadU(Ub + 6 * 8, u);  apply1q_win<2>(a, u);   // qubit 6
        loadU(Ub + 7 * 8, u);  apply1q_win<3>(a, u);   // qubit 7
        loadU(Ub + 8 * 8, u);  apply1q_win<4>(a, u);   // qubit 8
        crx_win<0, 1>(a, cs[8],  cs[9]);   // CRX(4,5)
        crx_win<1, 2>(a, cs[10], cs[11]);  // CRX(5,6)
        crx_win<2, 3>(a, cs[12], cs[13]);  // CRX(6,7)
        crx_win<3, 4>(a, cs[14], cs[15]);  // CRX(7,8)
        #pragma unroll
        for (int j = 0; j < 32; ++j) lds[SWZ(lo | (j << 4) | hi)] = a[j];
    }
    __syncthreads();

    // ---- SR3: window bits 8..12 (qubits 8..12): idx = tid | (j<<8)
    {
        #pragma unroll
        for (int j = 0; j < 32; ++j) a[j] = lds[SWZ(tid | (j << 8))];
        loadU(Ub + 9 * 8, u);   apply1q_win<1>(a, u);  // qubit 9
        loadU(Ub + 10 * 8, u);  apply1q_win<2>(a, u);  // qubit 10
        loadU(Ub + 11 * 8, u);  apply1q_win<3>(a, u);  // qubit 11
        loadU(Ub + 12 * 8, u);  apply1q_win<4>(a, u);  // qubit 12
        crx_win<0, 1>(a, cs[16], cs[17]);  // CRX(8,9)
        crx_win<1, 2>(a, cs[18], cs[19]);  // CRX(9,10)
        crx_win<2, 3>(a, cs[20], cs[21]);  // CRX(10,11)
        crx_win<3, 4>(a, cs[22], cs[23]);  // CRX(11,12)
        #pragma unroll
        for (int j = 0; j < 32; ++j) lds[SWZ(tid | (j << 8))] = a[j];
    }
    __syncthreads();

    #pragma unroll
    for (int j = 0; j < 32; ++j) state[base + j * 256 + tid] = lds[SWZ(j * 256 + tid)];
}

// ---------------- kernel 4: pass B (qubits 11..15 in regs, qubit 0 via shfl) ---------
// grid: 128 batches * 8 parts ; 256 threads ; t = outer bits 0..10
template<int LAYER>
__global__ __launch_bounds__(256) void qstep_b(const float* __restrict__ Uws,
                                               const float* __restrict__ crxcs,
                                               float2* __restrict__ state,
                                               float* __restrict__ ev) {
    int tid = threadIdx.x;
    int b = blockIdx.x >> 3, part = blockIdx.x & 7;
    int t = part * 256 + tid;                 // idx bits 0..10
    size_t base = ((size_t)b << 16) + t;
    float2 a[32];
    #pragma unroll
    for (int j = 0; j < 32; ++j) a[j] = state[base + ((size_t)j << 11)];

    const float* Ub = Uws + (size_t)(LAYER * 128 + b) * 128;
    const float* cs = crxcs + LAYER * 32;
    float u[8];
    // window: j bit k <-> qubit 11+k
    loadU(Ub + 13 * 8, u);  apply1q_win<2>(a, u);  // qubit 13
    loadU(Ub + 14 * 8, u);  apply1q_win<3>(a, u);  // qubit 14
    loadU(Ub + 15 * 8, u);  apply1q_win<4>(a, u);  // qubit 15
    crx_win<1, 2>(a, cs[24], cs[25]);  // CRX(12,13)
    crx_win<2, 3>(a, cs[26], cs[27]);  // CRX(13,14)
    crx_win<3, 4>(a, cs[28], cs[29]);  // CRX(14,15)
    // CRX(15,0): control = j bit 4, target = idx bit 0 = lane bit 0
    {
        float c = cs[30], s = cs[31];
        #pragma unroll
        for (int j = 16; j < 32; ++j) {
            float pr = __shfl_xor(a[j].x, 1);
            float pi = __shfl_xor(a[j].y, 1);
            float nr = c * a[j].x + s * pi;
            float ni = c * a[j].y - s * pr;
            a[j].x = nr; a[j].y = ni;
        }
    }

    if (LAYER == 0) {
        #pragma unroll
        for (int j = 0; j < 32; ++j) state[base + ((size_t)j << 11)] = a[j];
    } else {
        float P = 0.f, S0 = 0.f, S1 = 0.f, S2 = 0.f, S3 = 0.f, S4 = 0.f;
        #pragma unroll
        for (int j = 0; j < 32; ++j) {
            float pr = a[j].x * a[j].x + a[j].y * a[j].y;
            P += pr;
            S0 += (j & 1)  ? -pr : pr;
            S1 += (j & 2)  ? -pr : pr;
            S2 += (j & 4)  ? -pr : pr;
            S3 += (j & 8)  ? -pr : pr;
            S4 += (j & 16) ? -pr : pr;
        }
        float evq[16];
        #pragma unroll
        for (int q = 0; q < 11; ++q) evq[q] = ((t >> q) & 1) ? -P : P;
        evq[11] = S0; evq[12] = S1; evq[13] = S2; evq[14] = S3; evq[15] = S4;
        #pragma unroll
        for (int q = 0; q < 16; ++q) {
            float v = evq[q];
            #pragma unroll
            for (int o = 32; o >= 1; o >>= 1) v += __shfl_xor(v, o);
            evq[q] = v;
        }
        __shared__ float red[4][16];
        int wave = tid >> 6, lane = tid & 63;
        if (lane == 0) {
            #pragma unroll
            for (int q = 0; q < 16; ++q) red[wave][q] = evq[q];
        }
        __syncthreads();
        if (tid < 16) {
            float v = red[0][tid] + red[1][tid] + red[2][tid] + red[3][tid];
            atomicAdd(&ev[b * 16 + tid], v);
        }
    }
}

// ---------------- kernel 5: head + log_softmax ----------------
__global__ __launch_bounds__(128) void head_kernel(const float* __restrict__ ev,
                                                   const float* __restrict__ fcw,
                                                   const float* __restrict__ fcb,
                                                   float* __restrict__ out) {
    int b = threadIdx.x;
    if (b >= 128) return;
    float e[16];
    #pragma unroll
    for (int q = 0; q < 16; ++q) e[q] = ev[b * 16 + q];
    float lg[16];
    float mx = -1e30f;
    #pragma unroll
    for (int c = 0; c < 16; ++c) {
        float v = fcb[c];
        #pragma unroll
        for (int q = 0; q < 16; ++q) v += e[q] * fcw[c * 16 + q];
        lg[c] = v;
        mx = fmaxf(mx, v);
    }
    float se = 0.f;
    #pragma unroll
    for (int c = 0; c < 16; ++c) se += expf(lg[c] - mx);
    float lse = mx + logf(se);
    #pragma unroll
    for (int c = 0; c < 16; ++c) out[b * 16 + c] = lg[c] - lse;
}

// ---------------- launch ----------------
extern "C" void kernel_launch(void* const* d_in, const int* in_sizes, int n_in,
                              void* d_out, int out_size, void* d_ws, size_t ws_size,
                              hipStream_t stream) {
    const float* x    = (const float*)d_in[0];
    const float* cw   = (const float*)d_in[1];
    const float* cb   = (const float*)d_in[2];
    const float* rot1 = (const float*)d_in[3];
    const float* crx1 = (const float*)d_in[4];
    const float* rot2 = (const float*)d_in[5];
    const float* crx2 = (const float*)d_in[6];
    const float* fcw  = (const float*)d_in[7];
    const float* fcb  = (const float*)d_in[8];

    float* ws    = (float*)d_ws;
    float* p     = ws;                 // 4096 floats
    float* U     = ws + 4096;          // 2*128*16*8 = 32768 floats
    float* crxcs = ws + 36864;         // 64 floats
    float* ev    = ws + 36928;         // 2048 floats
    float2* state = (float2*)(ws + 40960);  // 128 * 65536 float2 = 64 MiB

    pool_kernel<<<4096, 256, 0, stream>>>(x, p);
    feats_kernel<<<128, 64, 0, stream>>>(p, cw, cb, rot1, crx1, rot2, crx2, U, crxcs, ev);
    qstep_a<0><<<1024, 256, 0, stream>>>(U, crxcs, state);
    qstep_b<0><<<1024, 256, 0, stream>>>(U, crxcs, state, ev);
    qstep_a<1><<<1024, 256, 0, stream>>>(U, crxcs, state);
    qstep_b<1><<<1024, 256, 0, stream>>>(U, crxcs, state, ev);
    head_kernel<<<1, 128, 0, stream>>>(ev, fcw, fcb, (float*)d_out);
}

// Round 2
// 114.809 us; speedup vs baseline: 1.6770x; 1.6770x over previous
//
#include <hip/hip_runtime.h>
#include <hip/hip_bf16.h>

// ---------------- helpers ----------------

// swizzle for 4096-amp LDS tile: XOR low 4 bits with bits 4-7 (bijective,
// uniform 4 lanes per bank-pair for all access patterns used below)
#define SWZA(i) ((i) ^ (((i) >> 4) & 15))

__device__ __forceinline__ void gate1q(float2& a0, float2& a1, const float* u) {
    // u: u00r,u00i,u01r,u01i,u10r,u10i,u11r,u11i ; new = U * [a0;a1]
    float n0r = u[0]*a0.x - u[1]*a0.y + u[2]*a1.x - u[3]*a1.y;
    float n0i = u[0]*a0.y + u[1]*a0.x + u[2]*a1.y + u[3]*a1.x;
    float n1r = u[4]*a0.x - u[5]*a0.y + u[6]*a1.x - u[7]*a1.y;
    float n1i = u[4]*a0.y + u[5]*a0.x + u[6]*a1.y + u[7]*a1.x;
    a0.x = n0r; a0.y = n0i; a1.x = n1r; a1.y = n1i;
}

__device__ __forceinline__ void crx_pair(float2& a0, float2& a1, float c, float s) {
    // RX on the (a0,a1) pair: n0 = c*a0 - i*s*a1 ; n1 = -i*s*a0 + c*a1
    float n0r = c*a0.x + s*a1.y;
    float n0i = c*a0.y - s*a1.x;
    float n1r = c*a1.x + s*a0.y;
    float n1i = c*a1.y - s*a0.x;
    a0.x = n0r; a0.y = n0i; a1.x = n1r; a1.y = n1i;
}

template<int K, int W>
__device__ __forceinline__ void apply1q_win(float2* a, const float* u) {
    #pragma unroll
    for (int m = 0; m < W / 2; ++m) {
        const int j0 = ((m >> K) << (K + 1)) | (m & ((1 << K) - 1));
        gate1q(a[j0], a[j0 | (1 << K)], u);
    }
}

template<int KC, int KT, int W>
__device__ __forceinline__ void crx_win(float2* a, float c, float s) {
    #pragma unroll
    for (int j = 0; j < W; ++j) {
        if ((j & (1 << KC)) != 0 && (j & (1 << KT)) == 0)
            crx_pair(a[j], a[j | (1 << KT)], c, s);
    }
}

__device__ __forceinline__ void loadU(const float* __restrict__ src, float* u) {
    #pragma unroll
    for (int k = 0; k < 8; ++k) u[k] = src[k];
}

// ---------------- kernel 1: adaptive pool ----------------
// x: (128, 2, 16, 64, 64) f32 -> p: (128, 32), p[b][c*16+dd*4+hh] = mean of 4x16x64 block
__global__ __launch_bounds__(256) void pool_kernel(const float* __restrict__ x,
                                                   float* __restrict__ p) {
    int blk = blockIdx.x;            // b*32 + j
    int b = blk >> 5, j = blk & 31;
    int c = j >> 4, dd = (j >> 2) & 3, hh = j & 3;
    const float4* xb = (const float4*)(x + (((size_t)(b * 2 + c) * 16 + dd * 4) << 12)
                                         + (size_t)hh * 1024);
    int tid = threadIdx.x;
    float sum = 0.f;
    #pragma unroll
    for (int k = 0; k < 4; ++k) {
        int f = k * 256 + tid;           // float4 index 0..1023
        int r = f >> 4, col = f & 15;    // row 0..63 (d'*16+h'), 16 float4 per row
        int off = (r >> 4) * 1024 + (r & 15) * 16 + col;  // float4 units
        float4 v = xb[off];
        sum += v.x + v.y + v.z + v.w;
    }
    #pragma unroll
    for (int o = 1; o < 64; o <<= 1) sum += __shfl_xor(sum, o);
    __shared__ float red[4];
    if ((tid & 63) == 0) red[tid >> 6] = sum;
    __syncthreads();
    if (tid == 0) p[blk] = (red[0] + red[1] + red[2] + red[3]) * (1.0f / 4096.0f);
}

// ---------------- kernel 2: feats + fused gate precompute ----------------
// U layout: U[l][b][q][8] floats ; crxcs[l][q][2] ; also zeroes ev[b][16]
__global__ __launch_bounds__(64) void feats_kernel(const float* __restrict__ p,
                                                   const float* __restrict__ cw,
                                                   const float* __restrict__ cb,
                                                   const float* __restrict__ rot1,
                                                   const float* __restrict__ crx1,
                                                   const float* __restrict__ rot2,
                                                   const float* __restrict__ crx2,
                                                   float* __restrict__ Uws,
                                                   float* __restrict__ crxcs,
                                                   float* __restrict__ ev) {
    int b = blockIdx.x, tid = threadIdx.x;
    __shared__ float pp[32];
    if (tid < 32) pp[tid] = p[b * 32 + tid];
    __syncthreads();
    if (tid >= 16 && tid < 32) ev[b * 16 + (tid - 16)] = 0.f;
    if (tid < 16) {
        int q = tid;
        float f = cb[q];
        #pragma unroll
        for (int jj = 0; jj < 32; ++jj) f += pp[jj] * cw[q * 32 + jj];
        float cr = cosf(0.5f * f), sr = sinf(0.5f * f);
        #pragma unroll
        for (int l = 0; l < 2; ++l) {
            const float* rw = (l == 0 ? rot1 : rot2) + q * 3;
            float phi = rw[0], th = rw[1], om = rw[2];
            float ct = cosf(0.5f * th), st = sinf(0.5f * th);
            float aa = 0.5f * (phi + om), dd = 0.5f * (phi - om);
            float ca = cosf(aa), sa = sinf(aa), cd = cosf(dd), sd = sinf(dd);
            // Rot = [[e^{-ia}ct, -e^{id}st], [e^{-id}st, e^{ia}ct]]
            float R00r =  ct * ca, R00i = -ct * sa;
            float R01r = -st * cd, R01i = -st * sd;
            float R10r =  st * cd, R10i = -st * sd;
            float R11r =  ct * ca, R11i =  ct * sa;
            // U = Rot * RX(f) , RX = [[cr, -i sr], [-i sr, cr]]
            float u0 = cr * R00r + sr * R01i;
            float u1 = cr * R00i - sr * R01r;
            float u2 = cr * R01r + sr * R00i;
            float u3 = cr * R01i - sr * R00r;
            float u4 = cr * R10r + sr * R11i;
            float u5 = cr * R10i - sr * R11r;
            float u6 = cr * R11r + sr * R10i;
            float u7 = cr * R11i - sr * R10r;
            float* dst = Uws + ((size_t)(l * 128 + b) * 16 + q) * 8;
            dst[0] = u0; dst[1] = u1; dst[2] = u2; dst[3] = u3;
            dst[4] = u4; dst[5] = u5; dst[6] = u6; dst[7] = u7;
            if (b == 0) {
                float th2 = (l == 0 ? crx1 : crx2)[q];
                crxcs[(l * 16 + q) * 2 + 0] = cosf(0.5f * th2);
                crxcs[(l * 16 + q) * 2 + 1] = sinf(0.5f * th2);
            }
        }
    }
}

// ---------------- kernel 3: pass A (qubits 0..11 local in 4096-amp LDS chunk) -------
// LAYER 0: grid = 128 (only chunk 0 is nonzero: state = e_0, gates touch bits 0-11)
// LAYER 1: grid = 128 batches * 16 chunks
// 256 threads ; LDS = 4096 float2 = 32 KB ; 16 amps/thread in registers
// Sub-round windows (overlapping 4-bit): {0-3}, {3-6}, {6-9}, {8-11}
template<int LAYER>
__global__ __launch_bounds__(256) void qstep_a(const float* __restrict__ Uws,
                                               const float* __restrict__ crxcs,
                                               float2* __restrict__ state) {
    __shared__ float2 lds[4096];
    int tid = threadIdx.x;
    int b, chunk;
    if (LAYER == 0) { b = blockIdx.x; chunk = 0; }
    else            { b = blockIdx.x >> 4; chunk = blockIdx.x & 15; }
    size_t base = ((size_t)b << 16) + ((size_t)chunk << 12);

    if (LAYER == 0) {
        #pragma unroll
        for (int j = 0; j < 16; ++j) lds[SWZA(j * 256 + tid)] = make_float2(0.f, 0.f);
        if (tid == 0) lds[SWZA(0)] = make_float2(1.f, 0.f);  // same thread wrote the zero
    } else {
        #pragma unroll
        for (int j = 0; j < 16; ++j) lds[SWZA(j * 256 + tid)] = state[base + j * 256 + tid];
    }
    __syncthreads();

    const float* Ub = Uws + (size_t)(LAYER * 128 + b) * 128;   // 16 gates * 8 floats
    const float* cs = crxcs + LAYER * 32;
    float2 a[16];
    float u[8];

    // ---- SR1: window bits 0..3 ; idx = (tid<<4) | j
    {
        #pragma unroll
        for (int j = 0; j < 16; ++j) a[j] = lds[SWZA((tid << 4) | j)];
        loadU(Ub + 0 * 8, u);  apply1q_win<0, 16>(a, u);   // U0
        loadU(Ub + 1 * 8, u);  apply1q_win<1, 16>(a, u);   // U1
        loadU(Ub + 2 * 8, u);  apply1q_win<2, 16>(a, u);   // U2
        loadU(Ub + 3 * 8, u);  apply1q_win<3, 16>(a, u);   // U3
        crx_win<0, 1, 16>(a, cs[0], cs[1]);    // CRX(0,1)
        crx_win<1, 2, 16>(a, cs[2], cs[3]);    // CRX(1,2)
        crx_win<2, 3, 16>(a, cs[4], cs[5]);    // CRX(2,3)
        #pragma unroll
        for (int j = 0; j < 16; ++j) lds[SWZA((tid << 4) | j)] = a[j];
    }
    __syncthreads();

    // ---- SR2: window bits 3..6 ; idx = (tid&7) | (j<<3) | ((tid>>3)<<7)
    {
        int lo = tid & 7, hi = (tid >> 3) << 7;
        #pragma unroll
        for (int j = 0; j < 16; ++j) a[j] = lds[SWZA(lo | (j << 3) | hi)];
        loadU(Ub + 4 * 8, u);  apply1q_win<1, 16>(a, u);   // U4 (bit 4 = k1)
        loadU(Ub + 5 * 8, u);  apply1q_win<2, 16>(a, u);   // U5
        loadU(Ub + 6 * 8, u);  apply1q_win<3, 16>(a, u);   // U6
        crx_win<0, 1, 16>(a, cs[6],  cs[7]);   // CRX(3,4)
        crx_win<1, 2, 16>(a, cs[8],  cs[9]);   // CRX(4,5)
        crx_win<2, 3, 16>(a, cs[10], cs[11]);  // CRX(5,6)
        #pragma unroll
        for (int j = 0; j < 16; ++j) lds[SWZA(lo | (j << 3) | hi)] = a[j];
    }
    __syncthreads();

    // ---- SR3: window bits 6..9 ; idx = (tid&63) | (j<<6) | ((tid>>6)<<10)
    {
        int lo = tid & 63, hi = (tid >> 6) << 10;
        #pragma unroll
        for (int j = 0; j < 16; ++j) a[j] = lds[SWZA(lo | (j << 6) | hi)];
        loadU(Ub + 7 * 8, u);  apply1q_win<1, 16>(a, u);   // U7 (bit 7 = k1)
        loadU(Ub + 8 * 8, u);  apply1q_win<2, 16>(a, u);   // U8
        loadU(Ub + 9 * 8, u);  apply1q_win<3, 16>(a, u);   // U9
        crx_win<0, 1, 16>(a, cs[12], cs[13]);  // CRX(6,7)
        crx_win<1, 2, 16>(a, cs[14], cs[15]);  // CRX(7,8)
        crx_win<2, 3, 16>(a, cs[16], cs[17]);  // CRX(8,9)
        #pragma unroll
        for (int j = 0; j < 16; ++j) lds[SWZA(lo | (j << 6) | hi)] = a[j];
    }
    __syncthreads();

    // ---- SR4: window bits 8..11 ; idx = tid | (j<<8)
    {
        #pragma unroll
        for (int j = 0; j < 16; ++j) a[j] = lds[SWZA(tid | (j << 8))];
        loadU(Ub + 10 * 8, u);  apply1q_win<2, 16>(a, u);  // U10 (bit 10 = k2)
        loadU(Ub + 11 * 8, u);  apply1q_win<3, 16>(a, u);  // U11
        crx_win<1, 2, 16>(a, cs[18], cs[19]);  // CRX(9,10)
        crx_win<2, 3, 16>(a, cs[20], cs[21]);  // CRX(10,11)
        #pragma unroll
        for (int j = 0; j < 16; ++j) lds[SWZA(tid | (j << 8))] = a[j];
    }
    __syncthreads();

    #pragma unroll
    for (int j = 0; j < 16; ++j) state[base + j * 256 + tid] = lds[SWZA(j * 256 + tid)];
}

// ---------------- kernel 4: pass B (qubits 11..15 in regs, qubit 0 via shfl) ---------
// grid: 128 batches * 8 parts ; 256 threads ; t = idx bits 0..10
// window: j bit k <-> qubit 11+k. Applies U12..U15, CRX(11,12)..(14,15), CRX(15,0).
// LAYER 0: only j=0,1 are nonzero on input (bits 12-15 of idx are zero after pass A).
template<int LAYER>
__global__ __launch_bounds__(256) void qstep_b(const float* __restrict__ Uws,
                                               const float* __restrict__ crxcs,
                                               float2* __restrict__ state,
                                               float* __restrict__ ev) {
    int tid = threadIdx.x;
    int b = blockIdx.x >> 3, part = blockIdx.x & 7;
    int t = part * 256 + tid;                 // idx bits 0..10
    size_t base = ((size_t)b << 16) + t;
    float2 a[32];
    if (LAYER == 0) {
        a[0] = state[base];
        a[1] = state[base + 2048];
        #pragma unroll
        for (int j = 2; j < 32; ++j) a[j] = make_float2(0.f, 0.f);
    } else {
        #pragma unroll
        for (int j = 0; j < 32; ++j) a[j] = state[base + ((size_t)j << 11)];
    }

    const float* Ub = Uws + (size_t)(LAYER * 128 + b) * 128;
    const float* cs = crxcs + LAYER * 32;
    float u[8];
    loadU(Ub + 12 * 8, u);  apply1q_win<1, 32>(a, u);  // U12 (bit 12 = k1)
    loadU(Ub + 13 * 8, u);  apply1q_win<2, 32>(a, u);  // U13
    loadU(Ub + 14 * 8, u);  apply1q_win<3, 32>(a, u);  // U14
    loadU(Ub + 15 * 8, u);  apply1q_win<4, 32>(a, u);  // U15
    crx_win<0, 1, 32>(a, cs[22], cs[23]);  // CRX(11,12)
    crx_win<1, 2, 32>(a, cs[24], cs[25]);  // CRX(12,13)
    crx_win<2, 3, 32>(a, cs[26], cs[27]);  // CRX(13,14)
    crx_win<3, 4, 32>(a, cs[28], cs[29]);  // CRX(14,15)
    // CRX(15,0): control = j bit 4 (qubit 15), target = idx bit 0 = lane bit 0
    {
        float c = cs[30], s = cs[31];
        #pragma unroll
        for (int j = 16; j < 32; ++j) {
            float pr = __shfl_xor(a[j].x, 1);
            float pi = __shfl_xor(a[j].y, 1);
            float nr = c * a[j].x + s * pi;
            float ni = c * a[j].y - s * pr;
            a[j].x = nr; a[j].y = ni;
        }
    }

    if (LAYER == 0) {
        #pragma unroll
        for (int j = 0; j < 32; ++j) state[base + ((size_t)j << 11)] = a[j];
    } else {
        float P = 0.f, S0 = 0.f, S1 = 0.f, S2 = 0.f, S3 = 0.f, S4 = 0.f;
        #pragma unroll
        for (int j = 0; j < 32; ++j) {
            float pr = a[j].x * a[j].x + a[j].y * a[j].y;
            P += pr;
            S0 += (j & 1)  ? -pr : pr;
            S1 += (j & 2)  ? -pr : pr;
            S2 += (j & 4)  ? -pr : pr;
            S3 += (j & 8)  ? -pr : pr;
            S4 += (j & 16) ? -pr : pr;
        }
        float evq[16];
        #pragma unroll
        for (int q = 0; q < 11; ++q) evq[q] = ((t >> q) & 1) ? -P : P;
        evq[11] = S0; evq[12] = S1; evq[13] = S2; evq[14] = S3; evq[15] = S4;
        #pragma unroll
        for (int q = 0; q < 16; ++q) {
            float v = evq[q];
            #pragma unroll
            for (int o = 32; o >= 1; o >>= 1) v += __shfl_xor(v, o);
            evq[q] = v;
        }
        __shared__ float red[4][16];
        int wave = tid >> 6, lane = tid & 63;
        if (lane == 0) {
            #pragma unroll
            for (int q = 0; q < 16; ++q) red[wave][q] = evq[q];
        }
        __syncthreads();
        if (tid < 16) {
            float v = red[0][tid] + red[1][tid] + red[2][tid] + red[3][tid];
            atomicAdd(&ev[b * 16 + tid], v);
        }
    }
}

// ---------------- kernel 5: head + log_softmax ----------------
__global__ __launch_bounds__(128) void head_kernel(const float* __restrict__ ev,
                                                   const float* __restrict__ fcw,
                                                   const float* __restrict__ fcb,
                                                   float* __restrict__ out) {
    int b = threadIdx.x;
    if (b >= 128) return;
    float e[16];
    #pragma unroll
    for (int q = 0; q < 16; ++q) e[q] = ev[b * 16 + q];
    float lg[16];
    float mx = -1e30f;
    #pragma unroll
    for (int c = 0; c < 16; ++c) {
        float v = fcb[c];
        #pragma unroll
        for (int q = 0; q < 16; ++q) v += e[q] * fcw[c * 16 + q];
        lg[c] = v;
        mx = fmaxf(mx, v);
    }
    float se = 0.f;
    #pragma unroll
    for (int c = 0; c < 16; ++c) se += expf(lg[c] - mx);
    float lse = mx + logf(se);
    #pragma unroll
    for (int c = 0; c < 16; ++c) out[b * 16 + c] = lg[c] - lse;
}

// ---------------- launch ----------------
extern "C" void kernel_launch(void* const* d_in, const int* in_sizes, int n_in,
                              void* d_out, int out_size, void* d_ws, size_t ws_size,
                              hipStream_t stream) {
    const float* x    = (const float*)d_in[0];
    const float* cw   = (const float*)d_in[1];
    const float* cb   = (const float*)d_in[2];
    const float* rot1 = (const float*)d_in[3];
    const float* crx1 = (const float*)d_in[4];
    const float* rot2 = (const float*)d_in[5];
    const float* crx2 = (const float*)d_in[6];
    const float* fcw  = (const float*)d_in[7];
    const float* fcb  = (const float*)d_in[8];

    float* ws    = (float*)d_ws;
    float* p     = ws;                 // 4096 floats
    float* U     = ws + 4096;          // 2*128*16*8 = 32768 floats
    float* crxcs = ws + 36864;         // 64 floats
    float* ev    = ws + 36928;         // 2048 floats
    float2* state = (float2*)(ws + 40960);  // 128 * 65536 float2 = 64 MiB

    pool_kernel<<<4096, 256, 0, stream>>>(x, p);
    feats_kernel<<<128, 64, 0, stream>>>(p, cw, cb, rot1, crx1, rot2, crx2, U, crxcs, ev);
    qstep_a<0><<<128,  256, 0, stream>>>(U, crxcs, state);
    qstep_b<0><<<1024, 256, 0, stream>>>(U, crxcs, state, ev);
    qstep_a<1><<<2048, 256, 0, stream>>>(U, crxcs, state);
    qstep_b<1><<<1024, 256, 0, stream>>>(U, crxcs, state, ev);
    head_kernel<<<1, 128, 0, stream>>>(ev, fcw, fcb, (float*)d_out);
}

// Round 3
// 105.428 us; speedup vs baseline: 1.8263x; 1.0890x over previous
//
#include <hip/hip_runtime.h>
#include <hip/hip_bf16.h>

// ---------------- helpers ----------------

// swizzle for 4096-amp LDS tile: XOR low 4 bits with bits 4-7 (bijective)
#define SWZA(i) ((i) ^ (((i) >> 4) & 15))

__device__ __forceinline__ void gate1q(float2& a0, float2& a1, const float* u) {
    // u: u00r,u00i,u01r,u01i,u10r,u10i,u11r,u11i ; new = U * [a0;a1]
    float n0r = u[0]*a0.x - u[1]*a0.y + u[2]*a1.x - u[3]*a1.y;
    float n0i = u[0]*a0.y + u[1]*a0.x + u[2]*a1.y + u[3]*a1.x;
    float n1r = u[4]*a0.x - u[5]*a0.y + u[6]*a1.x - u[7]*a1.y;
    float n1i = u[4]*a0.y + u[5]*a0.x + u[6]*a1.y + u[7]*a1.x;
    a0.x = n0r; a0.y = n0i; a1.x = n1r; a1.y = n1i;
}

__device__ __forceinline__ void crx_pair(float2& a0, float2& a1, float c, float s) {
    // RX on the (a0,a1) pair: n0 = c*a0 - i*s*a1 ; n1 = -i*s*a0 + c*a1
    float n0r = c*a0.x + s*a1.y;
    float n0i = c*a0.y - s*a1.x;
    float n1r = c*a1.x + s*a0.y;
    float n1i = c*a1.y - s*a0.x;
    a0.x = n0r; a0.y = n0i; a1.x = n1r; a1.y = n1i;
}

template<int K, int W>
__device__ __forceinline__ void apply1q_win(float2* a, const float* u) {
    #pragma unroll
    for (int m = 0; m < W / 2; ++m) {
        const int j0 = ((m >> K) << (K + 1)) | (m & ((1 << K) - 1));
        gate1q(a[j0], a[j0 | (1 << K)], u);
    }
}

template<int KC, int KT, int W>
__device__ __forceinline__ void crx_win(float2* a, float c, float s) {
    #pragma unroll
    for (int j = 0; j < W; ++j) {
        if ((j & (1 << KC)) != 0 && (j & (1 << KT)) == 0)
            crx_pair(a[j], a[j | (1 << KT)], c, s);
    }
}

__device__ __forceinline__ void loadU(const float* __restrict__ src, float* u) {
    #pragma unroll
    for (int k = 0; k < 8; ++k) u[k] = src[k];
}

// bf16x2 pack/unpack (RNE)
__device__ __forceinline__ unsigned bf2pack(float x, float y) {
    unsigned ux = __float_as_uint(x); ux = (ux + 0x7FFFu + ((ux >> 16) & 1u)) >> 16;
    unsigned uy = __float_as_uint(y); uy = (uy + 0x7FFFu + ((uy >> 16) & 1u)) >> 16;
    return ux | (uy << 16);
}
__device__ __forceinline__ float2 bf2unpack(unsigned v) {
    return make_float2(__uint_as_float(v << 16), __uint_as_float(v & 0xFFFF0000u));
}

// ---------------- kernel 1: adaptive pool ----------------
__global__ __launch_bounds__(256) void pool_kernel(const float* __restrict__ x,
                                                   float* __restrict__ p) {
    int blk = blockIdx.x;            // b*32 + j
    int b = blk >> 5, j = blk & 31;
    int c = j >> 4, dd = (j >> 2) & 3, hh = j & 3;
    const float4* xb = (const float4*)(x + (((size_t)(b * 2 + c) * 16 + dd * 4) << 12)
                                         + (size_t)hh * 1024);
    int tid = threadIdx.x;
    float sum = 0.f;
    #pragma unroll
    for (int k = 0; k < 4; ++k) {
        int f = k * 256 + tid;
        int r = f >> 4, col = f & 15;
        int off = (r >> 4) * 1024 + (r & 15) * 16 + col;
        float4 v = xb[off];
        sum += v.x + v.y + v.z + v.w;
    }
    #pragma unroll
    for (int o = 1; o < 64; o <<= 1) sum += __shfl_xor(sum, o);
    __shared__ float red[4];
    if ((tid & 63) == 0) red[tid >> 6] = sum;
    __syncthreads();
    if (tid == 0) p[blk] = (red[0] + red[1] + red[2] + red[3]) * (1.0f / 4096.0f);
}

// ---------------- kernel 2: feats + gate precompute + W0 (layer-0 B as 32x2) --------
__global__ __launch_bounds__(64) void feats_kernel(const float* __restrict__ p,
                                                   const float* __restrict__ cw,
                                                   const float* __restrict__ cb,
                                                   const float* __restrict__ rot1,
                                                   const float* __restrict__ crx1,
                                                   const float* __restrict__ rot2,
                                                   const float* __restrict__ crx2,
                                                   float* __restrict__ Uws,
                                                   float* __restrict__ crxcs,
                                                   float* __restrict__ ev,
                                                   float* __restrict__ w0f) {
    int b = blockIdx.x, tid = threadIdx.x;
    __shared__ float pp[32];
    __shared__ float uB[4][8];      // layer-0 U12..U15 for this batch
    if (tid < 32) pp[tid] = p[b * 32 + tid];
    __syncthreads();
    if (tid >= 16 && tid < 32) ev[b * 16 + (tid - 16)] = 0.f;
    if (tid < 16) {
        int q = tid;
        float f = cb[q];
        #pragma unroll
        for (int jj = 0; jj < 32; ++jj) f += pp[jj] * cw[q * 32 + jj];
        float cr = cosf(0.5f * f), sr = sinf(0.5f * f);
        #pragma unroll
        for (int l = 0; l < 2; ++l) {
            const float* rw = (l == 0 ? rot1 : rot2) + q * 3;
            float phi = rw[0], th = rw[1], om = rw[2];
            float ct = cosf(0.5f * th), st = sinf(0.5f * th);
            float aa = 0.5f * (phi + om), dd = 0.5f * (phi - om);
            float ca = cosf(aa), sa = sinf(aa), cd = cosf(dd), sd = sinf(dd);
            float R00r =  ct * ca, R00i = -ct * sa;
            float R01r = -st * cd, R01i = -st * sd;
            float R10r =  st * cd, R10i = -st * sd;
            float R11r =  ct * ca, R11i =  ct * sa;
            float u0 = cr * R00r + sr * R01i;
            float u1 = cr * R00i - sr * R01r;
            float u2 = cr * R01r + sr * R00i;
            float u3 = cr * R01i - sr * R00r;
            float u4 = cr * R10r + sr * R11i;
            float u5 = cr * R10i - sr * R11r;
            float u6 = cr * R11r + sr * R10i;
            float u7 = cr * R11i - sr * R10r;
            float* dst = Uws + ((size_t)(l * 128 + b) * 16 + q) * 8;
            dst[0] = u0; dst[1] = u1; dst[2] = u2; dst[3] = u3;
            dst[4] = u4; dst[5] = u5; dst[6] = u6; dst[7] = u7;
            if (l == 0 && q >= 12) {
                float* ub = uB[q - 12];
                ub[0] = u0; ub[1] = u1; ub[2] = u2; ub[3] = u3;
                ub[4] = u4; ub[5] = u5; ub[6] = u6; ub[7] = u7;
            }
            if (b == 0) {
                float th2 = (l == 0 ? crx1 : crx2)[q];
                crxcs[(l * 16 + q) * 2 + 0] = cosf(0.5f * th2);
                crxcs[(l * 16 + q) * 2 + 1] = sinf(0.5f * th2);
            }
        }
    }
    __syncthreads();
    // W0[b][m][j] = (layer-0 U12..U15 + CRX(11,12)..(14,15)) applied to e_j on the
    // 5-qubit window (bit k = qubit 11+k), restricted to input bits 12..15 = 0.
    if (tid >= 32 && tid < 34) {
        int j = tid - 32;
        float2 w[32];
        #pragma unroll
        for (int m = 0; m < 32; ++m) w[m] = make_float2(0.f, 0.f);
        w[j] = make_float2(1.f, 0.f);
        apply1q_win<1, 32>(w, uB[0]);   // U12
        apply1q_win<2, 32>(w, uB[1]);   // U13
        apply1q_win<3, 32>(w, uB[2]);   // U14
        apply1q_win<4, 32>(w, uB[3]);   // U15
        crx_win<0, 1, 32>(w, cosf(0.5f * crx1[11]), sinf(0.5f * crx1[11]));  // CRX(11,12)
        crx_win<1, 2, 32>(w, cosf(0.5f * crx1[12]), sinf(0.5f * crx1[12]));  // CRX(12,13)
        crx_win<2, 3, 32>(w, cosf(0.5f * crx1[13]), sinf(0.5f * crx1[13]));  // CRX(13,14)
        crx_win<3, 4, 32>(w, cosf(0.5f * crx1[14]), sinf(0.5f * crx1[14]));  // CRX(14,15)
        #pragma unroll
        for (int m = 0; m < 32; ++m) {
            float* d = w0f + ((size_t)(b * 32 + m) * 2 + j) * 2;
            d[0] = w[m].x; d[1] = w[m].y;
        }
    }
}

// ---------------- kernel 3: layer-0 pass A -> 4096-amp seed per batch ----------------
// grid = 128 ; 256 threads ; applies layer-0 U0..U11 + CRX(0,1)..(10,11) to e_0
__global__ __launch_bounds__(256) void qstep_a0(const float* __restrict__ Uws,
                                                const float* __restrict__ crxcs,
                                                float2* __restrict__ seed) {
    __shared__ float2 lds[4096];
    int tid = threadIdx.x;
    int b = blockIdx.x;

    #pragma unroll
    for (int j = 0; j < 16; ++j) lds[SWZA(j * 256 + tid)] = make_float2(0.f, 0.f);
    if (tid == 0) lds[SWZA(0)] = make_float2(1.f, 0.f);
    __syncthreads();

    const float* Ub = Uws + (size_t)b * 128;       // layer 0
    const float* cs = crxcs;                       // layer 0
    float2 a[16];
    float u[8];

    // SR1: bits 0..3
    {
        #pragma unroll
        for (int j = 0; j < 16; ++j) a[j] = lds[SWZA((tid << 4) | j)];
        loadU(Ub + 0 * 8, u);  apply1q_win<0, 16>(a, u);
        loadU(Ub + 1 * 8, u);  apply1q_win<1, 16>(a, u);
        loadU(Ub + 2 * 8, u);  apply1q_win<2, 16>(a, u);
        loadU(Ub + 3 * 8, u);  apply1q_win<3, 16>(a, u);
        crx_win<0, 1, 16>(a, cs[0], cs[1]);
        crx_win<1, 2, 16>(a, cs[2], cs[3]);
        crx_win<2, 3, 16>(a, cs[4], cs[5]);
        #pragma unroll
        for (int j = 0; j < 16; ++j) lds[SWZA((tid << 4) | j)] = a[j];
    }
    __syncthreads();

    // SR2: bits 3..6
    {
        int lo = tid & 7, hi = (tid >> 3) << 7;
        #pragma unroll
        for (int j = 0; j < 16; ++j) a[j] = lds[SWZA(lo | (j << 3) | hi)];
        loadU(Ub + 4 * 8, u);  apply1q_win<1, 16>(a, u);
        loadU(Ub + 5 * 8, u);  apply1q_win<2, 16>(a, u);
        loadU(Ub + 6 * 8, u);  apply1q_win<3, 16>(a, u);
        crx_win<0, 1, 16>(a, cs[6],  cs[7]);
        crx_win<1, 2, 16>(a, cs[8],  cs[9]);
        crx_win<2, 3, 16>(a, cs[10], cs[11]);
        #pragma unroll
        for (int j = 0; j < 16; ++j) lds[SWZA(lo | (j << 3) | hi)] = a[j];
    }
    __syncthreads();

    // SR3: bits 6..9
    {
        int lo = tid & 63, hi = (tid >> 6) << 10;
        #pragma unroll
        for (int j = 0; j < 16; ++j) a[j] = lds[SWZA(lo | (j << 6) | hi)];
        loadU(Ub + 7 * 8, u);  apply1q_win<1, 16>(a, u);
        loadU(Ub + 8 * 8, u);  apply1q_win<2, 16>(a, u);
        loadU(Ub + 9 * 8, u);  apply1q_win<3, 16>(a, u);
        crx_win<0, 1, 16>(a, cs[12], cs[13]);
        crx_win<1, 2, 16>(a, cs[14], cs[15]);
        crx_win<2, 3, 16>(a, cs[16], cs[17]);
        #pragma unroll
        for (int j = 0; j < 16; ++j) lds[SWZA(lo | (j << 6) | hi)] = a[j];
    }
    __syncthreads();

    // SR4: bits 8..11 ; store directly from regs (idx = tid | (j<<8))
    {
        #pragma unroll
        for (int j = 0; j < 16; ++j) a[j] = lds[SWZA(tid | (j << 8))];
        loadU(Ub + 10 * 8, u);  apply1q_win<2, 16>(a, u);
        loadU(Ub + 11 * 8, u);  apply1q_win<3, 16>(a, u);
        crx_win<1, 2, 16>(a, cs[18], cs[19]);
        crx_win<2, 3, 16>(a, cs[20], cs[21]);
        #pragma unroll
        for (int j = 0; j < 16; ++j) seed[((size_t)b << 12) + (j << 8) + tid] = a[j];
    }
}

// ---------------- kernel 4: layer-1 pass A with fused layer-0 B expansion ------------
// grid = 2048 (b = blk>>4, chunk = blk&15) ; 256 threads ; LDS 32 KB
// Loads the 4096-amp seed (L2-hot), applies W0 (+ runtime layer-0 CRX(15,0)),
// then layer-1 U0..U11 + CRX(0,1)..(10,11); writes bf16 state chunk.
__global__ __launch_bounds__(256) void qstep_a1(const float* __restrict__ Uws,
                                                const float* __restrict__ crxcs,
                                                const float* __restrict__ w0f,
                                                const float2* __restrict__ seed,
                                                unsigned* __restrict__ sbf) {
    __shared__ float2 lds[4096];
    int tid = threadIdx.x;
    int b = blockIdx.x >> 4, chunk = blockIdx.x & 15;

    // ---- fused layer-0 B: a[jj] for idx=(tid<<4)|jj (t = idx bits 0-10, bit11 = tid>>7)
    int t0 = (tid & 127) << 4;
    const float4* p0 = (const float4*)(seed + ((size_t)b << 12) + t0);
    const float4* p1 = (const float4*)(seed + ((size_t)b << 12) + 2048 + t0);
    float2 r0[16], r1[16];
    #pragma unroll
    for (int k = 0; k < 8; ++k) {
        float4 v = p0[k]; r0[2 * k] = make_float2(v.x, v.y); r0[2 * k + 1] = make_float2(v.z, v.w);
        float4 w = p1[k]; r1[2 * k] = make_float2(w.x, w.y); r1[2 * k + 1] = make_float2(w.z, w.w);
    }
    int m = (chunk << 1) | (tid >> 7);
    const float* wr = w0f + (size_t)(b * 32 + m) * 4;
    float w0r = wr[0], w0i = wr[1], w1r = wr[2], w1i = wr[3];
    float2 a[16];
    if (chunk >= 8) {   // m bit4 = 1 -> layer-0 CRX(15,0) active on these m
        float c = crxcs[30], s = crxcs[31];
        #pragma unroll
        for (int e = 0; e < 16; e += 2) {
            int o = e + 1;
            float2 v0e = make_float2(c * r0[e].x + s * r0[o].y, c * r0[e].y - s * r0[o].x);
            float2 v0o = make_float2(c * r0[o].x + s * r0[e].y, c * r0[o].y - s * r0[e].x);
            float2 v1e = make_float2(c * r1[e].x + s * r1[o].y, c * r1[e].y - s * r1[o].x);
            float2 v1o = make_float2(c * r1[o].x + s * r1[e].y, c * r1[o].y - s * r1[e].x);
            a[e].x = w0r * v0e.x - w0i * v0e.y + w1r * v1e.x - w1i * v1e.y;
            a[e].y = w0r * v0e.y + w0i * v0e.x + w1r * v1e.y + w1i * v1e.x;
            a[o].x = w0r * v0o.x - w0i * v0o.y + w1r * v1o.x - w1i * v1o.y;
            a[o].y = w0r * v0o.y + w0i * v0o.x + w1r * v1o.y + w1i * v1o.x;
        }
    } else {
        #pragma unroll
        for (int e = 0; e < 16; ++e) {
            a[e].x = w0r * r0[e].x - w0i * r0[e].y + w1r * r1[e].x - w1i * r1[e].y;
            a[e].y = w0r * r0[e].y + w0i * r0[e].x + w1r * r1[e].y + w1i * r1[e].x;
        }
    }

    const float* Ub = Uws + (size_t)(128 + b) * 128;   // layer 1
    const float* cs = crxcs + 32;                      // layer 1
    float u[8];

    // SR1: bits 0..3 (regs already in this layout)
    {
        loadU(Ub + 0 * 8, u);  apply1q_win<0, 16>(a, u);
        loadU(Ub + 1 * 8, u);  apply1q_win<1, 16>(a, u);
        loadU(Ub + 2 * 8, u);  apply1q_win<2, 16>(a, u);
        loadU(Ub + 3 * 8, u);  apply1q_win<3, 16>(a, u);
        crx_win<0, 1, 16>(a, cs[0], cs[1]);
        crx_win<1, 2, 16>(a, cs[2], cs[3]);
        crx_win<2, 3, 16>(a, cs[4], cs[5]);
        #pragma unroll
        for (int j = 0; j < 16; ++j) lds[SWZA((tid << 4) | j)] = a[j];
    }
    __syncthreads();

    // SR2: bits 3..6
    {
        int lo = tid & 7, hi = (tid >> 3) << 7;
        #pragma unroll
        for (int j = 0; j < 16; ++j) a[j] = lds[SWZA(lo | (j << 3) | hi)];
        loadU(Ub + 4 * 8, u);  apply1q_win<1, 16>(a, u);
        loadU(Ub + 5 * 8, u);  apply1q_win<2, 16>(a, u);
        loadU(Ub + 6 * 8, u);  apply1q_win<3, 16>(a, u);
        crx_win<0, 1, 16>(a, cs[6],  cs[7]);
        crx_win<1, 2, 16>(a, cs[8],  cs[9]);
        crx_win<2, 3, 16>(a, cs[10], cs[11]);
        #pragma unroll
        for (int j = 0; j < 16; ++j) lds[SWZA(lo | (j << 3) | hi)] = a[j];
    }
    __syncthreads();

    // SR3: bits 6..9
    {
        int lo = tid & 63, hi = (tid >> 6) << 10;
        #pragma unroll
        for (int j = 0; j < 16; ++j) a[j] = lds[SWZA(lo | (j << 6) | hi)];
        loadU(Ub + 7 * 8, u);  apply1q_win<1, 16>(a, u);
        loadU(Ub + 8 * 8, u);  apply1q_win<2, 16>(a, u);
        loadU(Ub + 9 * 8, u);  apply1q_win<3, 16>(a, u);
        crx_win<0, 1, 16>(a, cs[12], cs[13]);
        crx_win<1, 2, 16>(a, cs[14], cs[15]);
        crx_win<2, 3, 16>(a, cs[16], cs[17]);
        #pragma unroll
        for (int j = 0; j < 16; ++j) lds[SWZA(lo | (j << 6) | hi)] = a[j];
    }
    __syncthreads();

    // SR4: bits 8..11 ; store bf16 directly from regs (idx = tid | (j<<8))
    {
        #pragma unroll
        for (int j = 0; j < 16; ++j) a[j] = lds[SWZA(tid | (j << 8))];
        loadU(Ub + 10 * 8, u);  apply1q_win<2, 16>(a, u);
        loadU(Ub + 11 * 8, u);  apply1q_win<3, 16>(a, u);
        crx_win<1, 2, 16>(a, cs[18], cs[19]);
        crx_win<2, 3, 16>(a, cs[20], cs[21]);
        size_t base = ((size_t)b << 16) + ((size_t)chunk << 12);
        #pragma unroll
        for (int j = 0; j < 16; ++j)
            sbf[base + (j << 8) + tid] = bf2pack(a[j].x, a[j].y);
    }
}

// ---------------- kernel 5: layer-1 pass B + EV reduce (bf16 state in) ---------------
// grid: 1024 (b = blk>>3, part = blk&7) ; 256 threads ; t = idx bits 0..10
__global__ __launch_bounds__(256) void qstep_b1(const float* __restrict__ Uws,
                                                const float* __restrict__ crxcs,
                                                const unsigned* __restrict__ sbf,
                                                float* __restrict__ ev) {
    int tid = threadIdx.x;
    int b = blockIdx.x >> 3, part = blockIdx.x & 7;
    int t = part * 256 + tid;
    size_t base = ((size_t)b << 16) + t;
    float2 a[32];
    #pragma unroll
    for (int j = 0; j < 32; ++j) a[j] = bf2unpack(sbf[base + ((size_t)j << 11)]);

    const float* Ub = Uws + (size_t)(128 + b) * 128;
    const float* cs = crxcs + 32;
    float u[8];
    loadU(Ub + 12 * 8, u);  apply1q_win<1, 32>(a, u);
    loadU(Ub + 13 * 8, u);  apply1q_win<2, 32>(a, u);
    loadU(Ub + 14 * 8, u);  apply1q_win<3, 32>(a, u);
    loadU(Ub + 15 * 8, u);  apply1q_win<4, 32>(a, u);
    crx_win<0, 1, 32>(a, cs[22], cs[23]);
    crx_win<1, 2, 32>(a, cs[24], cs[25]);
    crx_win<2, 3, 32>(a, cs[26], cs[27]);
    crx_win<3, 4, 32>(a, cs[28], cs[29]);
    {   // CRX(15,0): control = j bit 4, target = idx bit 0 = lane bit 0
        float c = cs[30], s = cs[31];
        #pragma unroll
        for (int j = 16; j < 32; ++j) {
            float pr = __shfl_xor(a[j].x, 1);
            float pi = __shfl_xor(a[j].y, 1);
            float nr = c * a[j].x + s * pi;
            float ni = c * a[j].y - s * pr;
            a[j].x = nr; a[j].y = ni;
        }
    }

    float P = 0.f, S0 = 0.f, S1 = 0.f, S2 = 0.f, S3 = 0.f, S4 = 0.f;
    #pragma unroll
    for (int j = 0; j < 32; ++j) {
        float pr = a[j].x * a[j].x + a[j].y * a[j].y;
        P += pr;
        S0 += (j & 1)  ? -pr : pr;
        S1 += (j & 2)  ? -pr : pr;
        S2 += (j & 4)  ? -pr : pr;
        S3 += (j & 8)  ? -pr : pr;
        S4 += (j & 16) ? -pr : pr;
    }
    float evq[16];
    #pragma unroll
    for (int q = 0; q < 11; ++q) evq[q] = ((t >> q) & 1) ? -P : P;
    evq[11] = S0; evq[12] = S1; evq[13] = S2; evq[14] = S3; evq[15] = S4;
    #pragma unroll
    for (int q = 0; q < 16; ++q) {
        float v = evq[q];
        #pragma unroll
        for (int o = 32; o >= 1; o >>= 1) v += __shfl_xor(v, o);
        evq[q] = v;
    }
    __shared__ float red[4][16];
    int wave = tid >> 6, lane = tid & 63;
    if (lane == 0) {
        #pragma unroll
        for (int q = 0; q < 16; ++q) red[wave][q] = evq[q];
    }
    __syncthreads();
    if (tid < 16) {
        float v = red[0][tid] + red[1][tid] + red[2][tid] + red[3][tid];
        atomicAdd(&ev[b * 16 + tid], v);
    }
}

// ---------------- kernel 6: head + log_softmax ----------------
__global__ __launch_bounds__(128) void head_kernel(const float* __restrict__ ev,
                                                   const float* __restrict__ fcw,
                                                   const float* __restrict__ fcb,
                                                   float* __restrict__ out) {
    int b = threadIdx.x;
    if (b >= 128) return;
    float e[16];
    #pragma unroll
    for (int q = 0; q < 16; ++q) e[q] = ev[b * 16 + q];
    float lg[16];
    float mx = -1e30f;
    #pragma unroll
    for (int c = 0; c < 16; ++c) {
        float v = fcb[c];
        #pragma unroll
        for (int q = 0; q < 16; ++q) v += e[q] * fcw[c * 16 + q];
        lg[c] = v;
        mx = fmaxf(mx, v);
    }
    float se = 0.f;
    #pragma unroll
    for (int c = 0; c < 16; ++c) se += expf(lg[c] - mx);
    float lse = mx + logf(se);
    #pragma unroll
    for (int c = 0; c < 16; ++c) out[b * 16 + c] = lg[c] - lse;
}

// ---------------- launch ----------------
extern "C" void kernel_launch(void* const* d_in, const int* in_sizes, int n_in,
                              void* d_out, int out_size, void* d_ws, size_t ws_size,
                              hipStream_t stream) {
    const float* x    = (const float*)d_in[0];
    const float* cw   = (const float*)d_in[1];
    const float* cb   = (const float*)d_in[2];
    const float* rot1 = (const float*)d_in[3];
    const float* crx1 = (const float*)d_in[4];
    const float* rot2 = (const float*)d_in[5];
    const float* crx2 = (const float*)d_in[6];
    const float* fcw  = (const float*)d_in[7];
    const float* fcb  = (const float*)d_in[8];

    float* ws    = (float*)d_ws;
    float* p     = ws;                         // 4096
    float* U     = ws + 4096;                  // 32768 -> ends 36864
    float* crxcs = ws + 36864;                 // 64
    float* ev    = ws + 36928;                 // 2048 -> ends 38976
    float* w0f   = ws + 40960;                 // 16384 -> ends 57344
    float2* seed = (float2*)(ws + 65536);      // 128*4096 float2 = 4 MiB
    unsigned* sbf = (unsigned*)(ws + 1114112); // 128*65536 uint = 32 MiB

    pool_kernel<<<4096, 256, 0, stream>>>(x, p);
    feats_kernel<<<128, 64, 0, stream>>>(p, cw, cb, rot1, crx1, rot2, crx2,
                                         U, crxcs, ev, w0f);
    qstep_a0<<<128,  256, 0, stream>>>(U, crxcs, seed);
    qstep_a1<<<2048, 256, 0, stream>>>(U, crxcs, w0f, seed, sbf);
    qstep_b1<<<1024, 256, 0, stream>>>(U, crxcs, sbf, ev);
    head_kernel<<<1, 128, 0, stream>>>(ev, fcw, fcb, (float*)d_out);
}